// Round 11
// baseline (642.261 us; speedup 1.0000x reference)
//
#include <hip/hip_runtime.h>
#include <math.h>

#define D       128
#define NGRAPH  64
#define N0      1024
#define NE      (1<<20)
#define EPG     (NE/NGRAPH)      // 16384 edges per graph (contiguous slots)
#define NTOT    (NGRAPH*N0)
#define ASLOT   64               // max in-degree ~45 (Poisson 16); P(>64) ~ 1e-18

// ---- static device workspace (referenced ONLY from device code) ----
__device__ float g_h[NTOT*D];            // gathered features f32 (gather path)
__device__ float g_h2[NTOT*D];           // post-GEMM features
__device__ unsigned short g_mh[NTOT*D];  // mean  hi-plane (GEMM A, k<128)
__device__ unsigned short g_ml[NTOT*D];  // mean  lo-plane
__device__ unsigned short g_xh[NTOT*D];  // right hi-plane (GEMM A, k>=128)
__device__ unsigned short g_xl[NTOT*D];  // right lo-plane
__device__ unsigned short g_wbh[3*128*256]; // W stacked+transposed hi [r][c][k]
__device__ unsigned short g_wbl[3*128*256];
__device__ int   g_adjA[NTOT*ASLOT];     // ping-pong adjacency (rounds 0,2)
__device__ int   g_adjB[NTOT*ASLOT];     // round 1
__device__ int   g_cntA[NTOT];
__device__ int   g_cntB[NTOT];
__device__ float g_dot[NTOT];            // h2 . pw  (pre-tanh, pre-norm)
__device__ float g_pwnorm[3];
__device__ int   g_selidx[NGRAPH*820];
__device__ float g_selval[NGRAPH*820];
__device__ int   g_newid[NTOT];
__device__ float g_pool[3*NGRAPH*8*256]; // per-round partial readouts
typedef __attribute__((ext_vector_type(8))) short bf16x8;
typedef __attribute__((ext_vector_type(8))) unsigned short ushort8;
typedef __attribute__((ext_vector_type(4))) float f32x4;

__device__ inline unsigned short f2bf_rne(float f) {
    unsigned u = __float_as_uint(f);
    u += 0x7FFF + ((u >> 16) & 1);
    return (unsigned short)(u >> 16);
}
__device__ inline void split2(float v, unsigned short& h, unsigned short& l) {
    h = f2bf_rne(v);
    l = f2bf_rne(v - __uint_as_float((unsigned)h << 16));
}

// ---- prep: W stacked [Wl;Wr], transposed to [c][k], split hi/lo ----
__global__ void k_prep_w(const float* __restrict__ Wl1, const float* __restrict__ Wr1,
                         const float* __restrict__ Wl2, const float* __restrict__ Wr2,
                         const float* __restrict__ Wl3, const float* __restrict__ Wr3) {
    int t = blockIdx.x * 256 + threadIdx.x;      // < 3*128*256
    int r = t >> 15, rem = t & 32767;
    int c = rem >> 8, k = rem & 255;
    const float* WlR = (r == 0) ? Wl1 : (r == 1) ? Wl2 : Wl3;
    const float* WrR = (r == 0) ? Wr1 : (r == 1) ? Wr2 : Wr3;
    float v = (k < 128) ? WlR[k * 128 + c] : WrR[(k - 128) * 128 + c];
    split2(v, g_wbh[t], g_wbl[t]);
}

__global__ void k_norms(const float* __restrict__ p1, const float* __restrict__ p2,
                        const float* __restrict__ p3) {
    int r = blockIdx.x, lane = threadIdx.x;
    const float* p = (r == 0) ? p1 : (r == 1) ? p2 : p3;
    float a = p[lane], b = p[lane + 64];
    float s = a * a + b * b;
    for (int off = 32; off; off >>= 1) s += __shfl_xor(s, off);
    if (lane == 0) g_pwnorm[r] = sqrtf(s);
}

// ---- prep: round-0 x -> right-operand hi/lo planes ----
__global__ void k_prep_x(const float* __restrict__ x) {
    int t = blockIdx.x * 256 + threadIdx.x;      // < NTOT*D/4
    float4 v = ((const float4*)x)[t];
    ushort4 h4, l4;
    split2(v.x, h4.x, l4.x); split2(v.y, h4.y, l4.y);
    split2(v.z, h4.z, l4.z); split2(v.w, h4.w, l4.w);
    ((ushort4*)g_xh)[t] = h4;
    ((ushort4*)g_xl)[t] = l4;
}

// ---- round-0 adjacency: one block per graph, LDS slot counters ----
__global__ __launch_bounds__(1024) void k_badj0(const int* __restrict__ ei) {
    __shared__ int s_fill[N0];
    int g = blockIdx.x, tid = threadIdx.x;
    s_fill[tid] = 0;
    __syncthreads();
    int e0 = g * EPG;
#pragma unroll
    for (int i = 0; i < EPG / 1024; i++) {
        int e = e0 + i * 1024 + tid;
        int s = ei[e];
        int d = ei[NE + e];
        int slot = atomicAdd(&s_fill[d - g * N0], 1);
        if (slot < ASLOT) g_adjA[(size_t)d * ASLOT + slot] = s;
    }
    __syncthreads();
    g_cntA[g * N0 + tid] = min(s_fill[tid], ASLOT);
}

// ---- rounds 1-2: ballot-compact surviving adjacency (no atomics) ----
// dir=0: A->B (round1) ; dir=1: B->A (round2)
__global__ __launch_bounds__(256) void k_compact(int n_new, int dir) {
    int wid = threadIdx.x >> 6, lane = threadIdx.x & 63;
    int nj = blockIdx.x * 4 + wid;
    if (nj >= n_new) return;
    int old = g_selidx[nj];
    const int* adjO = dir ? g_adjB : g_adjA;
    const int* cntO = dir ? g_cntB : g_cntA;
    int* adjN = dir ? g_adjA : g_adjB;
    int* cntN = dir ? g_cntA : g_cntB;
    int cnt = cntO[old];
    int m = -1;
    if (lane < cnt) m = g_newid[adjO[(size_t)old * ASLOT + lane]];
    unsigned long long mask = __ballot(m >= 0);
    int pos = __popcll(mask & ((1ull << lane) - 1ull));
    if (m >= 0) adjN[(size_t)nj * ASLOT + pos] = m;
    if (lane == 0) cntN[nj] = __popcll(mask);
}

// ---- mean aggregation v2: LDS-staged feature slice, one block per (graph, 32-col chunk)
// 512 threads = 8 waves; each 32-lane half-wave owns one node at a time (stride 16).
// Gather = LDS reads (4 independent neighbor-quads in flight); emits hi/lo mean planes.
__global__ __launch_bounds__(512, 1) void k_aggregate(const float* __restrict__ x_in,
                                                      int use_input, int ab, int M) {
    __shared__ float tile[N0 * 33];              // 132 KB: x[g][:, c0:c0+32], pad 33
    const float* X = use_input ? x_in : g_h;
    const int* adj = ab ? g_adjB : g_adjA;
    const int* cntp = ab ? g_cntB : g_cntA;
    int b = blockIdx.x;
    int g = (b & 7) + 8 * (b >> 5);              // graph g -> XCD g%8 (all 4 chunks)
    int chunk = (b >> 3) & 3;
    int c0 = chunk * 32;
    int gbase = g * M;
    int tid = threadIdx.x;
    // stage slice: M rows x 32 cols (float4 per 8-lane group)
    for (int f = tid; f < M * 8; f += 512) {
        int row = f >> 3, cq = f & 7;
        *(float4*)&tile[row * 33 + cq * 4] =
            *(const float4*)&X[(size_t)(gbase + row) * 128 + c0 + cq * 4];
    }
    __syncthreads();
    int lane = tid & 63, wid = tid >> 6;
    int half = lane >> 5, li = lane & 31;
    int sg = li >> 3, cl = li & 7;               // 4 subgroups x 8 lanes per half
    for (int local = wid * 2 + half; local < M; local += 16) {
        int node = gbase + local;
        int cnt = cntp[node];
        size_t abase = (size_t)node * ASLOT;
        int a0 = adj[abase + li];                // preload full 64-slot window
        int a1 = adj[abase + 32 + li];           // (garbage beyond cnt is masked)
        float ax = 0.f, ay = 0.f, az = 0.f, aw = 0.f;
        for (int i16 = 0; i16 < cnt; i16 += 16) {
            int areg = (i16 < 32) ? a0 : a1;     // uniform within half
#pragma unroll
            for (int q = 0; q < 4; q++) {
                int idx = i16 + q * 4 + sg;
                int s = __shfl(areg, half * 32 + (idx & 31));
                bool ok = (idx < cnt);
                int sl = (ok ? s : node) - gbase;
                float4 v = *(const float4*)&tile[sl * 33 + cl * 4];
                float m = ok ? 1.f : 0.f;
                ax += m * v.x; ay += m * v.y; az += m * v.z; aw += m * v.w;
            }
        }
        // reduce the 4 subgroups within this 32-lane half
        ax += __shfl_xor(ax, 8);  ay += __shfl_xor(ay, 8);
        az += __shfl_xor(az, 8);  aw += __shfl_xor(aw, 8);
        ax += __shfl_xor(ax, 16); ay += __shfl_xor(ay, 16);
        az += __shfl_xor(az, 16); aw += __shfl_xor(aw, 16);
        if (sg == 0) {
            float inv = 1.f / (float)max(cnt, 1);
            ushort4 h4, l4;
            split2(ax * inv, h4.x, l4.x); split2(ay * inv, h4.y, l4.y);
            split2(az * inv, h4.z, l4.z); split2(aw * inv, h4.w, l4.w);
            *(ushort4*)&g_mh[(size_t)node * 128 + c0 + cl * 4] = h4;
            *(ushort4*)&g_ml[(size_t)node * 128 + c0 + cl * 4] = l4;
            if (chunk == 0 && cl == 0) g_dot[node] = 0.f;  // pre-zero for gemm atomics
        }
    }
}

// ---- fused SAGE GEMM (split-bf16 MFMA) + fused score dot ----
// h2 = relu([mean|xr] @ [Wl;Wr] + bl); g_dot[row] = h2[row] . pw
__global__ __launch_bounds__(256, 2) void k_gemm(int r,
                                                 const float* __restrict__ bl,
                                                 const float* __restrict__ pw) {
    __shared__ __align__(16) unsigned short sa_hi[128 * 40];
    __shared__ __align__(16) unsigned short sa_lo[128 * 40];
    __shared__ __align__(16) unsigned short sb_hi[128 * 40];
    __shared__ __align__(16) unsigned short sb_lo[128 * 40];
    const unsigned short* Wbh = g_wbh + r * 32768;
    const unsigned short* Wbl = g_wbl + r * 32768;
    int tid = threadIdx.x;
    int row0 = blockIdx.x * 128;
    int wid = tid >> 6, lane = tid & 63;
    int wr = wid >> 1, wc = wid & 1;
    int lrow = lane & 15, kgrp = lane >> 4;

    f32x4 acc[4][4];
#pragma unroll
    for (int mi = 0; mi < 4; mi++)
#pragma unroll
        for (int ni = 0; ni < 4; ni++)
#pragma unroll
            for (int q = 0; q < 4; q++) acc[mi][ni][q] = 0.f;

    for (int kc = 0; kc < 256; kc += 32) {
        const unsigned short* Ah = (kc < 128) ? g_mh : g_xh;
        const unsigned short* Al = (kc < 128) ? g_ml : g_xl;
        int kloc = kc & 127;
        __syncthreads();
#pragma unroll
        for (int i = 0; i < 2; i++) {            // A: 128 rows x 32 k, 2 planes
            int f = tid + i * 256;
            int row = f >> 2, kq = f & 3;
            size_t src = (size_t)(row0 + row) * 128 + kloc + kq * 8;
            *(ushort8*)&sa_hi[row * 40 + kq * 8] = *(const ushort8*)&Ah[src];
            *(ushort8*)&sa_lo[row * 40 + kq * 8] = *(const ushort8*)&Al[src];
        }
#pragma unroll
        for (int i = 0; i < 2; i++) {            // B: 128 cols x 32 k, 2 planes
            int f = tid + i * 256;
            int c = f >> 2, kq = f & 3;
            size_t src = (size_t)c * 256 + kc + kq * 8;
            *(ushort8*)&sb_hi[c * 40 + kq * 8] = *(const ushort8*)&Wbh[src];
            *(ushort8*)&sb_lo[c * 40 + kq * 8] = *(const ushort8*)&Wbl[src];
        }
        __syncthreads();
        bf16x8 ah[4], al[4], bh[4], blo[4];
#pragma unroll
        for (int mi = 0; mi < 4; mi++) {
            int rr = wr * 64 + mi * 16 + lrow;
            ah[mi] = *(const bf16x8*)&sa_hi[rr * 40 + kgrp * 8];
            al[mi] = *(const bf16x8*)&sa_lo[rr * 40 + kgrp * 8];
        }
#pragma unroll
        for (int ni = 0; ni < 4; ni++) {
            int c = wc * 64 + ni * 16 + lrow;
            bh[ni]  = *(const bf16x8*)&sb_hi[c * 40 + kgrp * 8];
            blo[ni] = *(const bf16x8*)&sb_lo[c * 40 + kgrp * 8];
        }
#pragma unroll
        for (int mi = 0; mi < 4; mi++)
#pragma unroll
            for (int ni = 0; ni < 4; ni++) {
                acc[mi][ni] = __builtin_amdgcn_mfma_f32_16x16x32_bf16(ah[mi], bh[ni],  acc[mi][ni], 0, 0, 0);
                acc[mi][ni] = __builtin_amdgcn_mfma_f32_16x16x32_bf16(ah[mi], blo[ni], acc[mi][ni], 0, 0, 0);
                acc[mi][ni] = __builtin_amdgcn_mfma_f32_16x16x32_bf16(al[mi], bh[ni],  acc[mi][ni], 0, 0, 0);
            }
    }
    // epilogue: C/D col = lane&15, row = (lane>>4)*4 + reg; fused pw-dot
    float pwv[4];
#pragma unroll
    for (int ni = 0; ni < 4; ni++) pwv[ni] = pw[wc * 64 + ni * 16 + lrow];
#pragma unroll
    for (int mi = 0; mi < 4; mi++) {
        float dotq[4] = {0.f, 0.f, 0.f, 0.f};
#pragma unroll
        for (int ni = 0; ni < 4; ni++) {
            int c = wc * 64 + ni * 16 + lrow;
            float b = bl[c];
#pragma unroll
            for (int q = 0; q < 4; q++) {
                float v = fmaxf(acc[mi][ni][q] + b, 0.f);
                g_h2[(size_t)(row0 + wr * 64 + mi * 16 + kgrp * 4 + q) * 128 + c] = v;
                dotq[q] += v * pwv[ni];
            }
        }
#pragma unroll
        for (int q = 0; q < 4; q++) {
            float dv = dotq[q];
            dv += __shfl_xor(dv, 1); dv += __shfl_xor(dv, 2);
            dv += __shfl_xor(dv, 4); dv += __shfl_xor(dv, 8);
            if (lrow == 0)
                atomicAdd(&g_dot[row0 + wr * 64 + mi * 16 + kgrp * 4 + q], dv);
        }
    }
}

// ---- per-graph top-K on raw dots (tanh monotonic); selval = tanh(dot/||pw||) ----
__global__ void k_topk(int M, int K, int rr) {
    __shared__ float sc[1024];
    __shared__ int   id[1024];
    int g = blockIdx.x, tid = threadIdx.x;
    float invn = 1.f / g_pwnorm[rr];
    for (int i = tid; i < 1024; i += 512) {
        sc[i] = (i < M) ? g_dot[g * M + i] : -INFINITY;
        id[i] = i;
    }
    for (int i = tid; i < M; i += 512) g_newid[g * M + i] = -1;
    __syncthreads();
    for (int k = 2; k <= 1024; k <<= 1) {
        for (int j = k >> 1; j > 0; j >>= 1) {
            for (int i = tid; i < 1024; i += 512) {
                int ixj = i ^ j;
                if (ixj > i) {
                    bool desc = ((i & k) == 0);
                    float a = sc[i], b = sc[ixj];
                    bool sw = desc ? (a < b) : (a > b);
                    if (sw) {
                        sc[i] = b; sc[ixj] = a;
                        int t = id[i]; id[i] = id[ixj]; id[ixj] = t;
                    }
                }
            }
            __syncthreads();
        }
    }
    for (int j = tid; j < K; j += 512) {
        int li = id[j];
        g_selidx[g * K + j] = g * M + li;
        g_selval[g * K + j] = tanhf(sc[j] * invn);
        g_newid[g * M + li] = g * K + j;
    }
}

// ---- gather x_new = h2[sel]*val -> g_h (f32) + hi/lo planes; partial readout ----
__global__ void k_gather_pool(int K, int rr) {
    int g = blockIdx.x, chunk = blockIdx.y;   // linear b%8 = g%8 (XCD locality)
    int cs = (K + 7) / 8;
    int j0 = chunk * cs, j1 = min(K, j0 + cs);
    int tid = threadIdx.x;
    int c = tid & 127, half = tid >> 7;
    float mx = -INFINITY, sm = 0.f;
    for (int j = j0 + half; j < j1; j += 2) {
        int srcRow = g_selidx[g * K + j];
        float v = g_h2[(size_t)srcRow * 128 + c] * g_selval[g * K + j];
        size_t o = (size_t)(g * K + j) * 128 + c;
        g_h[o] = v;
        split2(v, g_xh[o], g_xl[o]);
        mx = fmaxf(mx, v); sm += v;
    }
    __shared__ float smx[256], ssm[256];
    smx[tid] = mx; ssm[tid] = sm;
    __syncthreads();
    if (half == 0) {
        mx = fmaxf(mx, smx[tid + 128]);
        sm += ssm[tid + 128];
        g_pool[((rr * NGRAPH + g) * 8 + chunk) * 256 + c] = mx;
        g_pool[((rr * NGRAPH + g) * 8 + chunk) * 256 + 128 + c] = sm;
    }
}

// ---- final MLP head (fused 3-round readout combine) ----
__global__ void k_mlp(const float* __restrict__ W1, const float* __restrict__ b1,
                      const float* __restrict__ W2, const float* __restrict__ b2,
                      const float* __restrict__ W3, const float* __restrict__ b3,
                      float* __restrict__ out, int K0, int K1, int K2) {
    int g = blockIdx.x, tid = threadIdx.x;   // 128 threads
    __shared__ float s_sh[256], h1[128], h2v[64], red[128];
    float Kf[3] = {(float)K0, (float)K1, (float)K2};
    float accmax = 0.f, accmean = 0.f;
    for (int r = 0; r < 3; r++) {
        float mx = -INFINITY, sm = 0.f;
        for (int ch = 0; ch < 8; ch++) {
            const float* p = &g_pool[((r * NGRAPH + g) * 8 + ch) * 256];
            mx = fmaxf(mx, p[tid]);
            sm += p[128 + tid];
        }
        accmax += mx;
        accmean += sm / Kf[r];
    }
    s_sh[tid] = accmax; s_sh[128 + tid] = accmean;
    __syncthreads();
    float a = 0.f;
    for (int k = 0; k < 256; k++) a += s_sh[k] * W1[k * 128 + tid];
    h1[tid] = fmaxf(a + b1[tid], 0.f);
    __syncthreads();
    if (tid < 64) {
        float a2 = 0.f;
        for (int k = 0; k < 128; k++) a2 += h1[k] * W2[k * 64 + tid];
        h2v[tid] = fmaxf(a2 + b2[tid], 0.f);
    }
    __syncthreads();
    red[tid] = (tid < 64) ? h2v[tid] * W3[tid] : 0.f;
    __syncthreads();
    for (int s = 64; s > 0; s >>= 1) {
        if (tid < s) red[tid] += red[tid + s];
        __syncthreads();
    }
    if (tid == 0) {
        float z = red[0] + b3[0];
        out[g] = 1.f / (1.f + expf(-z));
    }
}

extern "C" void kernel_launch(void* const* d_in, const int* in_sizes, int n_in,
                              void* d_out, int out_size, void* d_ws, size_t ws_size,
                              hipStream_t stream) {
    const float* x  = (const float*)d_in[0];
    const int*   ei = (const int*)d_in[1];
    const float* Wl[3] = {(const float*)d_in[2], (const float*)d_in[6],  (const float*)d_in[10]};
    const float* bl[3] = {(const float*)d_in[3], (const float*)d_in[7],  (const float*)d_in[11]};
    const float* Wr[3] = {(const float*)d_in[4], (const float*)d_in[8],  (const float*)d_in[12]};
    const float* pw[3] = {(const float*)d_in[5], (const float*)d_in[9],  (const float*)d_in[13]};
    const float* W1 = (const float*)d_in[14]; const float* b1 = (const float*)d_in[15];
    const float* W2 = (const float*)d_in[16]; const float* b2 = (const float*)d_in[17];
    const float* W3 = (const float*)d_in[18]; const float* b3 = (const float*)d_in[19];
    float* out = (float*)d_out;

    const int Ms[3] = {1024, 820, 656};
    const int Ks[3] = {820, 656, 525};

    k_prep_w<<<384, 256, 0, stream>>>(Wl[0], Wr[0], Wl[1], Wr[1], Wl[2], Wr[2]);
    k_norms<<<3, 64, 0, stream>>>(pw[0], pw[1], pw[2]);
    k_prep_x<<<NTOT * D / 4 / 256, 256, 0, stream>>>(x);

    for (int r = 0; r < 3; r++) {
        int M = Ms[r], K = Ks[r];
        int n = NGRAPH * M;                  // 65536 / 52480 / 41984 (all %128==0)
        int ab = (r == 1) ? 1 : 0;           // adjacency buffer for this round
        if (r == 0)
            k_badj0<<<NGRAPH, 1024, 0, stream>>>(ei);
        else
            k_compact<<<(n + 3) / 4, 256, 0, stream>>>(n, r - 1); // r=1: A->B, r=2: B->A
        k_aggregate<<<NGRAPH * 4, 512, 0, stream>>>(x, (r == 0) ? 1 : 0, ab, M);
        k_gemm<<<n / 128, 256, 0, stream>>>(r, bl[r], pw[r]);
        k_topk<<<NGRAPH, 512, 0, stream>>>(M, K, r);
        k_gather_pool<<<dim3(NGRAPH, 8), 256, 0, stream>>>(K, r);
    }
    k_mlp<<<NGRAPH, 128, 0, stream>>>(W1, b1, W2, b2, W3, b3, out,
                                      Ks[0], Ks[1], Ks[2]);
}

// Round 12
// 512.575 us; speedup vs baseline: 1.2530x; 1.2530x over previous
//
#include <hip/hip_runtime.h>
#include <math.h>

#define D       128
#define NGRAPH  64
#define N0      1024
#define NE      (1<<20)
#define EPG     (NE/NGRAPH)      // 16384 edges per graph (contiguous slots)
#define NTOT    (NGRAPH*N0)
#define ASLOT   64               // max in-degree ~45 (Poisson 16); P(>64) ~ 1e-18

// ---- static device workspace (referenced ONLY from device code) ----
__device__ float g_h[NTOT*D];            // gathered features f32 (gather path)
__device__ float g_h2[NTOT*D];           // post-GEMM features
__device__ unsigned short g_mh[NTOT*D];  // mean  hi-plane (GEMM A, k<128)
__device__ unsigned short g_ml[NTOT*D];  // mean  lo-plane
__device__ unsigned short g_xh[NTOT*D];  // right hi-plane (GEMM A, k>=128)
__device__ unsigned short g_xl[NTOT*D];  // right lo-plane
__device__ unsigned short g_wbh[3*128*256]; // W stacked+transposed hi [r][c][k]
__device__ unsigned short g_wbl[3*128*256];
__device__ int   g_adjA[NTOT*ASLOT];     // ping-pong adjacency (rounds 0,2)
__device__ int   g_adjB[NTOT*ASLOT];     // round 1
__device__ int   g_cntA[NTOT];
__device__ int   g_cntB[NTOT];
__device__ float g_dot[NTOT];            // h2 . pw  (pre-tanh, pre-norm)
__device__ float g_pwnorm[3];
__device__ int   g_selidx[NGRAPH*820];
__device__ float g_selval[NGRAPH*820];
__device__ int   g_newid[NTOT];
__device__ float g_pool[3*NGRAPH*8*256]; // per-round partial readouts
typedef __attribute__((ext_vector_type(8))) short bf16x8;
typedef __attribute__((ext_vector_type(8))) unsigned short ushort8;
typedef __attribute__((ext_vector_type(4))) float f32x4;

__device__ inline unsigned short f2bf_rne(float f) {
    unsigned u = __float_as_uint(f);
    u += 0x7FFF + ((u >> 16) & 1);
    return (unsigned short)(u >> 16);
}
__device__ inline void split2(float v, unsigned short& h, unsigned short& l) {
    h = f2bf_rne(v);
    l = f2bf_rne(v - __uint_as_float((unsigned)h << 16));
}

// ---- prep: W stacked [Wl;Wr], transposed to [c][k], split hi/lo ----
__global__ void k_prep_w(const float* __restrict__ Wl1, const float* __restrict__ Wr1,
                         const float* __restrict__ Wl2, const float* __restrict__ Wr2,
                         const float* __restrict__ Wl3, const float* __restrict__ Wr3) {
    int t = blockIdx.x * 256 + threadIdx.x;      // < 3*128*256
    int r = t >> 15, rem = t & 32767;
    int c = rem >> 8, k = rem & 255;
    const float* WlR = (r == 0) ? Wl1 : (r == 1) ? Wl2 : Wl3;
    const float* WrR = (r == 0) ? Wr1 : (r == 1) ? Wr2 : Wr3;
    float v = (k < 128) ? WlR[k * 128 + c] : WrR[(k - 128) * 128 + c];
    split2(v, g_wbh[t], g_wbl[t]);
}

__global__ void k_norms(const float* __restrict__ p1, const float* __restrict__ p2,
                        const float* __restrict__ p3) {
    int r = blockIdx.x, lane = threadIdx.x;
    const float* p = (r == 0) ? p1 : (r == 1) ? p2 : p3;
    float a = p[lane], b = p[lane + 64];
    float s = a * a + b * b;
    for (int off = 32; off; off >>= 1) s += __shfl_xor(s, off);
    if (lane == 0) g_pwnorm[r] = sqrtf(s);
}

// ---- prep: round-0 x -> right-operand hi/lo planes ----
__global__ void k_prep_x(const float* __restrict__ x) {
    int t = blockIdx.x * 256 + threadIdx.x;      // < NTOT*D/4
    float4 v = ((const float4*)x)[t];
    ushort4 h4, l4;
    split2(v.x, h4.x, l4.x); split2(v.y, h4.y, l4.y);
    split2(v.z, h4.z, l4.z); split2(v.w, h4.w, l4.w);
    ((ushort4*)g_xh)[t] = h4;
    ((ushort4*)g_xl)[t] = l4;
}

// ---- round-0 adjacency: one block per graph, LDS slot counters ----
__global__ __launch_bounds__(1024) void k_badj0(const int* __restrict__ ei) {
    __shared__ int s_fill[N0];
    int g = blockIdx.x, tid = threadIdx.x;
    s_fill[tid] = 0;
    __syncthreads();
    int e0 = g * EPG;
#pragma unroll
    for (int i = 0; i < EPG / 1024; i++) {
        int e = e0 + i * 1024 + tid;
        int s = ei[e];
        int d = ei[NE + e];
        int slot = atomicAdd(&s_fill[d - g * N0], 1);
        if (slot < ASLOT) g_adjA[(size_t)d * ASLOT + slot] = s;
    }
    __syncthreads();
    g_cntA[g * N0 + tid] = min(s_fill[tid], ASLOT);
}

// ---- rounds 1-2: ballot-compact surviving adjacency (no atomics) ----
// dir=0: A->B (round1) ; dir=1: B->A (round2)
__global__ __launch_bounds__(256) void k_compact(int n_new, int dir) {
    int wid = threadIdx.x >> 6, lane = threadIdx.x & 63;
    int nj = blockIdx.x * 4 + wid;
    if (nj >= n_new) return;
    int old = g_selidx[nj];
    const int* adjO = dir ? g_adjB : g_adjA;
    const int* cntO = dir ? g_cntB : g_cntA;
    int* adjN = dir ? g_adjA : g_adjB;
    int* cntN = dir ? g_cntA : g_cntB;
    int cnt = cntO[old];
    int m = -1;
    if (lane < cnt) m = g_newid[adjO[(size_t)old * ASLOT + lane]];
    unsigned long long mask = __ballot(m >= 0);
    int pos = __popcll(mask & ((1ull << lane) - 1ull));
    if (m >= 0) adjN[(size_t)nj * ASLOT + pos] = m;
    if (lane == 0) cntN[nj] = __popcll(mask);
}

// ---- mean aggregation (round-10 known-good): wave = 2 nodes, shfl-broadcast,
// 4-way ILP gather from L2 (graph slices are XCD-L2-resident via the g%8 swizzle).
// LDS-staged variant measured WORSE (r11: 95us, 4.8M bank conflicts, 20% occ).
__global__ __launch_bounds__(256) void k_aggregate(const float* __restrict__ x_in,
                                                   int use_input, int ab, int M, int BPG) {
    const float* X = use_input ? x_in : g_h;
    const int* adj = ab ? g_adjB : g_adjA;
    const int* cntp = ab ? g_cntB : g_cntA;
    int b = blockIdx.x;
    int j = b >> 3;
    int g = (b & 7) + 8 * (j / BPG);
    int ib = j % BPG;
    int wid = threadIdx.x >> 6, lane = threadIdx.x & 63;
    int half = lane >> 5, li = lane & 31;
    int local = ib * 8 + wid * 2 + half;
    int node = g * M + local;
    int cnt = (local < M) ? cntp[node] : 0;
    int cnt2 = max(cnt, __shfl_xor(cnt, 32));
    float ax = 0.f, ay = 0.f, az = 0.f, aw = 0.f;
    const float4* Xp = (const float4*)X;
    size_t abase = (size_t)node * ASLOT;
    for (int base = 0; base < cnt2; base += 32) {
        int a = (base + li < cnt) ? adj[abase + base + li] : -1;
        int mm = min(cnt2 - base, 32);
        int mmr = (mm + 3) & ~3;
        for (int i = 0; i < mmr; i += 4) {
            int s0 = __shfl(a, half * 32 + i + 0);
            int s1 = __shfl(a, half * 32 + i + 1);
            int s2 = __shfl(a, half * 32 + i + 2);
            int s3 = __shfl(a, half * 32 + i + 3);
            float4 v0 = Xp[(size_t)max(s0, 0) * 32 + li];
            float4 v1 = Xp[(size_t)max(s1, 0) * 32 + li];
            float4 v2 = Xp[(size_t)max(s2, 0) * 32 + li];
            float4 v3 = Xp[(size_t)max(s3, 0) * 32 + li];
            float m0 = (s0 >= 0) ? 1.f : 0.f, m1 = (s1 >= 0) ? 1.f : 0.f;
            float m2 = (s2 >= 0) ? 1.f : 0.f, m3 = (s3 >= 0) ? 1.f : 0.f;
            ax += m0 * v0.x + m1 * v1.x + m2 * v2.x + m3 * v3.x;
            ay += m0 * v0.y + m1 * v1.y + m2 * v2.y + m3 * v3.y;
            az += m0 * v0.z + m1 * v1.z + m2 * v2.z + m3 * v3.z;
            aw += m0 * v0.w + m1 * v1.w + m2 * v2.w + m3 * v3.w;
        }
    }
    if (local < M) {
        float inv = 1.f / (float)max(cnt, 1);
        ushort4 h4, l4;
        split2(ax * inv, h4.x, l4.x); split2(ay * inv, h4.y, l4.y);
        split2(az * inv, h4.z, l4.z); split2(aw * inv, h4.w, l4.w);
        *(ushort4*)&g_mh[(size_t)node * 128 + li * 4] = h4;
        *(ushort4*)&g_ml[(size_t)node * 128 + li * 4] = l4;
        if (li == 0) g_dot[node] = 0.f;   // per-node zero (both halves covered)
    }
}

// ---- fused SAGE GEMM (split-bf16 MFMA) + fused score dot ----
// h2 = relu([mean|xr] @ [Wl;Wr] + bl); g_dot[row] = h2[row] . pw
__global__ __launch_bounds__(256, 2) void k_gemm(int r,
                                                 const float* __restrict__ bl,
                                                 const float* __restrict__ pw) {
    __shared__ __align__(16) unsigned short sa_hi[128 * 40];
    __shared__ __align__(16) unsigned short sa_lo[128 * 40];
    __shared__ __align__(16) unsigned short sb_hi[128 * 40];
    __shared__ __align__(16) unsigned short sb_lo[128 * 40];
    const unsigned short* Wbh = g_wbh + r * 32768;
    const unsigned short* Wbl = g_wbl + r * 32768;
    int tid = threadIdx.x;
    int row0 = blockIdx.x * 128;
    int wid = tid >> 6, lane = tid & 63;
    int wr = wid >> 1, wc = wid & 1;
    int lrow = lane & 15, kgrp = lane >> 4;

    f32x4 acc[4][4];
#pragma unroll
    for (int mi = 0; mi < 4; mi++)
#pragma unroll
        for (int ni = 0; ni < 4; ni++)
#pragma unroll
            for (int q = 0; q < 4; q++) acc[mi][ni][q] = 0.f;

    for (int kc = 0; kc < 256; kc += 32) {
        const unsigned short* Ah = (kc < 128) ? g_mh : g_xh;
        const unsigned short* Al = (kc < 128) ? g_ml : g_xl;
        int kloc = kc & 127;
        __syncthreads();
#pragma unroll
        for (int i = 0; i < 2; i++) {            // A: 128 rows x 32 k, 2 planes
            int f = tid + i * 256;
            int row = f >> 2, kq = f & 3;
            size_t src = (size_t)(row0 + row) * 128 + kloc + kq * 8;
            *(ushort8*)&sa_hi[row * 40 + kq * 8] = *(const ushort8*)&Ah[src];
            *(ushort8*)&sa_lo[row * 40 + kq * 8] = *(const ushort8*)&Al[src];
        }
#pragma unroll
        for (int i = 0; i < 2; i++) {            // B: 128 cols x 32 k, 2 planes
            int f = tid + i * 256;
            int c = f >> 2, kq = f & 3;
            size_t src = (size_t)c * 256 + kc + kq * 8;
            *(ushort8*)&sb_hi[c * 40 + kq * 8] = *(const ushort8*)&Wbh[src];
            *(ushort8*)&sb_lo[c * 40 + kq * 8] = *(const ushort8*)&Wbl[src];
        }
        __syncthreads();
        bf16x8 ah[4], al[4], bh[4], blo[4];
#pragma unroll
        for (int mi = 0; mi < 4; mi++) {
            int rr = wr * 64 + mi * 16 + lrow;
            ah[mi] = *(const bf16x8*)&sa_hi[rr * 40 + kgrp * 8];
            al[mi] = *(const bf16x8*)&sa_lo[rr * 40 + kgrp * 8];
        }
#pragma unroll
        for (int ni = 0; ni < 4; ni++) {
            int c = wc * 64 + ni * 16 + lrow;
            bh[ni]  = *(const bf16x8*)&sb_hi[c * 40 + kgrp * 8];
            blo[ni] = *(const bf16x8*)&sb_lo[c * 40 + kgrp * 8];
        }
#pragma unroll
        for (int mi = 0; mi < 4; mi++)
#pragma unroll
            for (int ni = 0; ni < 4; ni++) {
                acc[mi][ni] = __builtin_amdgcn_mfma_f32_16x16x32_bf16(ah[mi], bh[ni],  acc[mi][ni], 0, 0, 0);
                acc[mi][ni] = __builtin_amdgcn_mfma_f32_16x16x32_bf16(ah[mi], blo[ni], acc[mi][ni], 0, 0, 0);
                acc[mi][ni] = __builtin_amdgcn_mfma_f32_16x16x32_bf16(al[mi], bh[ni],  acc[mi][ni], 0, 0, 0);
            }
    }
    // epilogue: C/D col = lane&15, row = (lane>>4)*4 + reg; fused pw-dot
    float pwv[4];
#pragma unroll
    for (int ni = 0; ni < 4; ni++) pwv[ni] = pw[wc * 64 + ni * 16 + lrow];
#pragma unroll
    for (int mi = 0; mi < 4; mi++) {
        float dotq[4] = {0.f, 0.f, 0.f, 0.f};
#pragma unroll
        for (int ni = 0; ni < 4; ni++) {
            int c = wc * 64 + ni * 16 + lrow;
            float b = bl[c];
#pragma unroll
            for (int q = 0; q < 4; q++) {
                float v = fmaxf(acc[mi][ni][q] + b, 0.f);
                g_h2[(size_t)(row0 + wr * 64 + mi * 16 + kgrp * 4 + q) * 128 + c] = v;
                dotq[q] += v * pwv[ni];
            }
        }
#pragma unroll
        for (int q = 0; q < 4; q++) {
            float dv = dotq[q];
            dv += __shfl_xor(dv, 1); dv += __shfl_xor(dv, 2);
            dv += __shfl_xor(dv, 4); dv += __shfl_xor(dv, 8);
            if (lrow == 0)
                atomicAdd(&g_dot[row0 + wr * 64 + mi * 16 + kgrp * 4 + q], dv);
        }
    }
}

// ---- per-graph top-K on raw dots (tanh monotonic); selval = tanh(dot/||pw||) ----
__global__ void k_topk(int M, int K, int rr) {
    __shared__ float sc[1024];
    __shared__ int   id[1024];
    int g = blockIdx.x, tid = threadIdx.x;
    float invn = 1.f / g_pwnorm[rr];
    for (int i = tid; i < 1024; i += 512) {
        sc[i] = (i < M) ? g_dot[g * M + i] : -INFINITY;
        id[i] = i;
    }
    for (int i = tid; i < M; i += 512) g_newid[g * M + i] = -1;
    __syncthreads();
    for (int k = 2; k <= 1024; k <<= 1) {
        for (int j = k >> 1; j > 0; j >>= 1) {
            for (int i = tid; i < 1024; i += 512) {
                int ixj = i ^ j;
                if (ixj > i) {
                    bool desc = ((i & k) == 0);
                    float a = sc[i], b = sc[ixj];
                    bool sw = desc ? (a < b) : (a > b);
                    if (sw) {
                        sc[i] = b; sc[ixj] = a;
                        int t = id[i]; id[i] = id[ixj]; id[ixj] = t;
                    }
                }
            }
            __syncthreads();
        }
    }
    for (int j = tid; j < K; j += 512) {
        int li = id[j];
        g_selidx[g * K + j] = g * M + li;
        g_selval[g * K + j] = tanhf(sc[j] * invn);
        g_newid[g * M + li] = g * K + j;
    }
}

// ---- gather x_new = h2[sel]*val -> g_h (f32) + hi/lo planes; partial readout ----
__global__ void k_gather_pool(int K, int rr) {
    int g = blockIdx.x, chunk = blockIdx.y;   // linear b%8 = g%8 (XCD locality)
    int cs = (K + 7) / 8;
    int j0 = chunk * cs, j1 = min(K, j0 + cs);
    int tid = threadIdx.x;
    int c = tid & 127, half = tid >> 7;
    float mx = -INFINITY, sm = 0.f;
    for (int j = j0 + half; j < j1; j += 2) {
        int srcRow = g_selidx[g * K + j];
        float v = g_h2[(size_t)srcRow * 128 + c] * g_selval[g * K + j];
        size_t o = (size_t)(g * K + j) * 128 + c;
        g_h[o] = v;
        split2(v, g_xh[o], g_xl[o]);
        mx = fmaxf(mx, v); sm += v;
    }
    __shared__ float smx[256], ssm[256];
    smx[tid] = mx; ssm[tid] = sm;
    __syncthreads();
    if (half == 0) {
        mx = fmaxf(mx, smx[tid + 128]);
        sm += ssm[tid + 128];
        g_pool[((rr * NGRAPH + g) * 8 + chunk) * 256 + c] = mx;
        g_pool[((rr * NGRAPH + g) * 8 + chunk) * 256 + 128 + c] = sm;
    }
}

// ---- final MLP head (fused 3-round readout combine) ----
__global__ void k_mlp(const float* __restrict__ W1, const float* __restrict__ b1,
                      const float* __restrict__ W2, const float* __restrict__ b2,
                      const float* __restrict__ W3, const float* __restrict__ b3,
                      float* __restrict__ out, int K0, int K1, int K2) {
    int g = blockIdx.x, tid = threadIdx.x;   // 128 threads
    __shared__ float s_sh[256], h1[128], h2v[64], red[128];
    float Kf[3] = {(float)K0, (float)K1, (float)K2};
    float accmax = 0.f, accmean = 0.f;
    for (int r = 0; r < 3; r++) {
        float mx = -INFINITY, sm = 0.f;
        for (int ch = 0; ch < 8; ch++) {
            const float* p = &g_pool[((r * NGRAPH + g) * 8 + ch) * 256];
            mx = fmaxf(mx, p[tid]);
            sm += p[128 + tid];
        }
        accmax += mx;
        accmean += sm / Kf[r];
    }
    s_sh[tid] = accmax; s_sh[128 + tid] = accmean;
    __syncthreads();
    float a = 0.f;
    for (int k = 0; k < 256; k++) a += s_sh[k] * W1[k * 128 + tid];
    h1[tid] = fmaxf(a + b1[tid], 0.f);
    __syncthreads();
    if (tid < 64) {
        float a2 = 0.f;
        for (int k = 0; k < 128; k++) a2 += h1[k] * W2[k * 64 + tid];
        h2v[tid] = fmaxf(a2 + b2[tid], 0.f);
    }
    __syncthreads();
    red[tid] = (tid < 64) ? h2v[tid] * W3[tid] : 0.f;
    __syncthreads();
    for (int s = 64; s > 0; s >>= 1) {
        if (tid < s) red[tid] += red[tid + s];
        __syncthreads();
    }
    if (tid == 0) {
        float z = red[0] + b3[0];
        out[g] = 1.f / (1.f + expf(-z));
    }
}

extern "C" void kernel_launch(void* const* d_in, const int* in_sizes, int n_in,
                              void* d_out, int out_size, void* d_ws, size_t ws_size,
                              hipStream_t stream) {
    const float* x  = (const float*)d_in[0];
    const int*   ei = (const int*)d_in[1];
    const float* Wl[3] = {(const float*)d_in[2], (const float*)d_in[6],  (const float*)d_in[10]};
    const float* bl[3] = {(const float*)d_in[3], (const float*)d_in[7],  (const float*)d_in[11]};
    const float* Wr[3] = {(const float*)d_in[4], (const float*)d_in[8],  (const float*)d_in[12]};
    const float* pw[3] = {(const float*)d_in[5], (const float*)d_in[9],  (const float*)d_in[13]};
    const float* W1 = (const float*)d_in[14]; const float* b1 = (const float*)d_in[15];
    const float* W2 = (const float*)d_in[16]; const float* b2 = (const float*)d_in[17];
    const float* W3 = (const float*)d_in[18]; const float* b3 = (const float*)d_in[19];
    float* out = (float*)d_out;

    const int Ms[3] = {1024, 820, 656};
    const int Ks[3] = {820, 656, 525};

    k_prep_w<<<384, 256, 0, stream>>>(Wl[0], Wr[0], Wl[1], Wr[1], Wl[2], Wr[2]);
    k_norms<<<3, 64, 0, stream>>>(pw[0], pw[1], pw[2]);
    k_prep_x<<<NTOT * D / 4 / 256, 256, 0, stream>>>(x);

    for (int r = 0; r < 3; r++) {
        int M = Ms[r], K = Ks[r];
        int n = NGRAPH * M;                  // 65536 / 52480 / 41984 (all %128==0)
        int BPG = (M + 7) / 8;
        int ab = (r == 1) ? 1 : 0;           // adjacency buffer for this round
        if (r == 0)
            k_badj0<<<NGRAPH, 1024, 0, stream>>>(ei);
        else
            k_compact<<<(n + 3) / 4, 256, 0, stream>>>(n, r - 1); // r=1: A->B, r=2: B->A
        k_aggregate<<<NGRAPH * BPG, 256, 0, stream>>>(x, (r == 0) ? 1 : 0, ab, M, BPG);
        k_gemm<<<n / 128, 256, 0, stream>>>(r, bl[r], pw[r]);
        k_topk<<<NGRAPH, 512, 0, stream>>>(M, K, r);
        k_gather_pool<<<dim3(NGRAPH, 8), 256, 0, stream>>>(K, r);
    }
    k_mlp<<<NGRAPH, 128, 0, stream>>>(W1, b1, W2, b2, W3, b3, out,
                                      Ks[0], Ks[1], Ks[2]);
}